// Round 5
// baseline (223.985 us; speedup 1.0000x reference)
//
#include <hip/hip_runtime.h>
#include <hip/hip_bf16.h>

typedef unsigned short u16;
typedef unsigned int u32;
typedef __bf16 bf16x8 __attribute__((ext_vector_type(8)));
typedef float f32x4 __attribute__((ext_vector_type(4)));
typedef u16 u16x8 __attribute__((ext_vector_type(8)));
typedef u32 u32x2 __attribute__((ext_vector_type(2)));
typedef u32 u32x4 __attribute__((ext_vector_type(4)));

#define S_LEN 2048
#define DMODEL 512
#define NHEAD 8
#define DHEAD 64
// log2(e); Q is pre-scaled by 0.125*LOG2E so softmax runs in exp2 domain.
#define QSCALE 0.1803368801111204f
#define MASKC 1.4426950409e9f
#define RESCALE_THR 8.0f

static __device__ __forceinline__ u16 f2bf(float f) {
    union { float f; unsigned u; } cv; cv.f = f;
    unsigned u = cv.u;
    return (u16)((u + 0x7fffu + ((u >> 16) & 1u)) >> 16);  // RNE
}
static __device__ __forceinline__ u32 pk2bf(float a, float b) {
    union { __hip_bfloat162 h; u32 u; } cv;
    float2 f2; f2.x = a; f2.y = b;
    cv.h = __float22bfloat162_rn(f2);
    return cv.u;
}
static __device__ __forceinline__ bf16x8 ld8(const u16* p) {
    return *(const bf16x8*)p;
}
// load 8 f32, convert to bf16x8 in-register (RNE — bitwise identical to prep's cvt)
static __device__ __forceinline__ bf16x8 ld8f(const float* p) {
    f32x4 a = *(const f32x4*)p;
    f32x4 b = *(const f32x4*)(p + 4);
    u32x4 w;
    w[0] = pk2bf(a[0], a[1]); w[1] = pk2bf(a[2], a[3]);
    w[2] = pk2bf(b[0], b[1]); w[3] = pk2bf(b[2], b[3]);
    union { u32x4 u; bf16x8 h; } cv; cv.u = w; return cv.h;
}
static __device__ __forceinline__ float fmax3(float a, float b, float c) {
    return __builtin_fmaxf(__builtin_fmaxf(a, b), c);  // clang fuses to v_max3_f32
}

// ---------------- prep: weight transpose->bf16 | mask flags ----------------
// grid.x partition: [0,1024) transpose_w, [1024,3072) mask flags. 256 thr.
__global__ __launch_bounds__(256) void prep_kernel(
    const float* __restrict__ w0, const float* __restrict__ w1,
    const float* __restrict__ w2, const float* __restrict__ w3,
    const float* __restrict__ mask,
    u16* __restrict__ wtall, int* __restrict__ flags) {
    const int p = blockIdx.x;
    const int tid = threadIdx.x;
    __shared__ float t[32][33];
    __shared__ int wred[4];
    if (p < 1024) {
        // W (512x512 fp32) -> Wt bf16 (N x K). slot order in wtall: [wo, wq, wk, wv]
        const int z = p >> 8, rem = p & 255, by = rem >> 4, bx = rem & 15;
        const float* in = (z == 0) ? w0 : (z == 1) ? w1 : (z == 2) ? w2 : w3;
        u16* o = wtall + (long)(((z + 1) & 3)) * 262144;
        const int tx = tid & 31, ty = tid >> 5;
#pragma unroll
        for (int i = 0; i < 4; ++i)
            t[ty + 8 * i][tx] = in[(by * 32 + ty + 8 * i) * DMODEL + bx * 32 + tx];
        __syncthreads();
#pragma unroll
        for (int i = 0; i < 4; ++i)
            o[(bx * 32 + ty + 8 * i) * DMODEL + by * 32 + tx] = f2bf(t[tx][ty + 8 * i]);
    } else {
        const int bid = p - 1024;  // 2*32*32
        const int b = bid >> 10, qt = (bid >> 5) & 31, kt = bid & 31;
        const int r = tid >> 2, cs = tid & 3;
        const float* mp = mask + ((long)(b * S_LEN + qt * 64 + r)) * S_LEN + kt * 64 + cs * 16;
        int nz = 0;
#pragma unroll
        for (int j = 0; j < 4; ++j) {
            f32x4 a = *(const f32x4*)(mp + j * 4);
            nz |= (a[0] != 0.f) | (a[1] != 0.f) | (a[2] != 0.f) | (a[3] != 0.f);
        }
        unsigned long long ball = __ballot(nz);
        if ((tid & 63) == 0) wred[tid >> 6] = (ball != 0ull) ? 1 : 0;
        __syncthreads();
        if (tid == 0) flags[bid] = wred[0] | wred[1] | wred[2] | wred[3];
    }
}

// ---------------- GEMM pieces ----------------
// Shared epilogue: C(4096x512) += bias; vtout writes per-head transposed Vt (B,H,DH,S).
template <bool F32OUT, int TM>
static __device__ __forceinline__ void store_c(f32x4 (&acc)[TM][2],
                                               const float* __restrict__ bias,
                                               void* __restrict__ Cp, float oscale,
                                               bool vtout, int m0, int n0, int cidx, int kg) {
    if (vtout) {
        const int bb = m0 >> 11;  // batch (tile never crosses the 2048 boundary)
#pragma unroll
        for (int j = 0; j < 2; ++j) {
            int col = n0 + j * 16 + cidx;
            float bv = bias[col];
            u16* vt = (u16*)Cp + (((long)(bb * 8 + (col >> 6))) * 64 + (col & 63)) * S_LEN;
#pragma unroll
            for (int i = 0; i < TM; ++i) {
                int s = (m0 + i * 16 + kg * 4) & (S_LEN - 1);
                u32x2 d;
                d[0] = pk2bf(acc[i][j][0] + bv, acc[i][j][1] + bv);
                d[1] = pk2bf(acc[i][j][2] + bv, acc[i][j][3] + bv);
                *(u32x2*)(vt + s) = d;
            }
        }
        return;
    }
#pragma unroll
    for (int j = 0; j < 2; ++j) {
        int col = n0 + j * 16 + cidx;
        float bv = bias[col];
#pragma unroll
        for (int i = 0; i < TM; ++i) {
#pragma unroll
            for (int r = 0; r < 4; ++r) {
                int row = m0 + i * 16 + kg * 4 + r;
                float val = (acc[i][j][r] + bv) * oscale;
                if (F32OUT) {
                    ((float*)Cp)[(long)row * DMODEL + col] = val;
                } else {
                    ((u16*)Cp)[(long)row * DMODEL + col] = f2bf(val);
                }
            }
        }
    }
}

// bf16-A GEMM (out projection)
template <bool F32OUT, int TM>
static __device__ __forceinline__ void gemm_body(const u16* __restrict__ A,
                                                 const u16* __restrict__ Wt,
                                                 const float* __restrict__ bias,
                                                 void* __restrict__ Cp, float oscale,
                                                 bool vtout, int bx, int by) {
    const int lane = threadIdx.x & 63;
    const int wave = threadIdx.x >> 6;
    const int wr = wave >> 1, wc = wave & 1;
    const int m0 = by * (TM * 32) + wr * (TM * 16);
    const int n0 = bx * 64 + wc * 32;
    const int cidx = lane & 15;
    const int kg = lane >> 4;

    const u16* aptr[TM];
    const u16* bptr[2];
#pragma unroll
    for (int t = 0; t < TM; ++t)
        aptr[t] = A + (long)(m0 + t * 16 + cidx) * DMODEL + kg * 8;
#pragma unroll
    for (int t = 0; t < 2; ++t)
        bptr[t] = Wt + (long)(n0 + t * 16 + cidx) * DMODEL + kg * 8;

    const f32x4 fz = {0.f, 0.f, 0.f, 0.f};
    f32x4 acc[TM][2];
#pragma unroll
    for (int i = 0; i < TM; ++i)
#pragma unroll
        for (int j = 0; j < 2; ++j) acc[i][j] = fz;

#pragma unroll 4
    for (int k0 = 0; k0 < 512; k0 += 32) {
        bf16x8 a[TM], b[2];
#pragma unroll
        for (int t = 0; t < TM; ++t) a[t] = ld8(aptr[t] + k0);
#pragma unroll
        for (int t = 0; t < 2; ++t) b[t] = ld8(bptr[t] + k0);
#pragma unroll
        for (int i = 0; i < TM; ++i)
#pragma unroll
            for (int j = 0; j < 2; ++j)
                acc[i][j] = __builtin_amdgcn_mfma_f32_16x16x32_bf16(a[i], b[j], acc[i][j], 0, 0, 0);
    }
    store_c<F32OUT, TM>(acc, bias, Cp, oscale, vtout, m0, n0, cidx, kg);
}

// f32-A GEMM (qkv projections): reads original f32 activations, cvt->bf16 in-register.
template <int TM>
static __device__ __forceinline__ void gemm_body_af32(const float* __restrict__ A,
                                                      const u16* __restrict__ Wt,
                                                      const float* __restrict__ bias,
                                                      void* __restrict__ Cp, float oscale,
                                                      bool vtout, int bx, int by) {
    const int lane = threadIdx.x & 63;
    const int wave = threadIdx.x >> 6;
    const int wr = wave >> 1, wc = wave & 1;
    const int m0 = by * (TM * 32) + wr * (TM * 16);
    const int n0 = bx * 64 + wc * 32;
    const int cidx = lane & 15;
    const int kg = lane >> 4;

    const float* aptr[TM];
    const u16* bptr[2];
#pragma unroll
    for (int t = 0; t < TM; ++t)
        aptr[t] = A + (long)(m0 + t * 16 + cidx) * DMODEL + kg * 8;
#pragma unroll
    for (int t = 0; t < 2; ++t)
        bptr[t] = Wt + (long)(n0 + t * 16 + cidx) * DMODEL + kg * 8;

    const f32x4 fz = {0.f, 0.f, 0.f, 0.f};
    f32x4 acc[TM][2];
#pragma unroll
    for (int i = 0; i < TM; ++i)
#pragma unroll
        for (int j = 0; j < 2; ++j) acc[i][j] = fz;

#pragma unroll 2
    for (int k0 = 0; k0 < 512; k0 += 32) {
        bf16x8 a[TM], b[2];
#pragma unroll
        for (int t = 0; t < TM; ++t) a[t] = ld8f(aptr[t] + k0);
#pragma unroll
        for (int t = 0; t < 2; ++t) b[t] = ld8(bptr[t] + k0);
#pragma unroll
        for (int i = 0; i < TM; ++i)
#pragma unroll
            for (int j = 0; j < 2; ++j)
                acc[i][j] = __builtin_amdgcn_mfma_f32_16x16x32_bf16(a[i], b[j], acc[i][j], 0, 0, 0);
    }
    store_c<false, TM>(acc, bias, Cp, oscale, vtout, m0, n0, cidx, kg);
}

// XCD-aware swizzle (T1): dispatch order round-robins XCDs; remap so the 8 bx-blocks
// sharing one A row-panel all land on ONE XCD -> A panel fetched into that L2 once.
// Requires gridY % 8 == 0. Bijective: (xcd, j) <-> flat.
static __device__ __forceinline__ void xcd_swizzle(int gridX, int gridY, int& bx, int& by) {
    const int flat = blockIdx.x + gridX * blockIdx.y;
    const int xcd = flat & 7;
    const int j = flat >> 3;
    by = xcd * (gridY >> 3) + j / gridX;
    bx = j % gridX;
}

__global__ __launch_bounds__(256) void qkv_gemm_kernel(
    const float* __restrict__ Aq, const float* __restrict__ Ak, const float* __restrict__ Av,
    const u16* __restrict__ wtall,
    const float* __restrict__ bq, const float* __restrict__ bk, const float* __restrict__ bv,
    u16* __restrict__ Q, u16* __restrict__ K, u16* __restrict__ Vt) {
    const float* A = (blockIdx.z == 0) ? Aq : (blockIdx.z == 1) ? Ak : Av;
    const u16* W = wtall + (long)(blockIdx.z + 1) * 262144;  // [wo, wq, wk, wv]
    const float* b;
    u16* C;
    float sc = 1.f;
    bool vt = false;
    if (blockIdx.z == 0) { b = bq; C = Q; sc = QSCALE; }  // fold 1/sqrt(DH)*log2e into Q
    else if (blockIdx.z == 1) { b = bk; C = K; }
    else { b = bv; C = Vt; vt = true; }
    int bx, by;
    xcd_swizzle(8, 32, bx, by);
    gemm_body_af32<4>(A, W, b, C, sc, vt, bx, by);
}

__global__ __launch_bounds__(256) void out_gemm_kernel(const u16* __restrict__ A,
                                                       const u16* __restrict__ Wt,
                                                       const float* __restrict__ bias,
                                                       float* __restrict__ C) {
    int bx, by;
    xcd_swizzle(8, 64, bx, by);
    gemm_body<true, 2>(A, Wt, bias, C, 1.f, false, bx, by);
}

// ---------------- flash attention, S^T formulation ----------------
// grid: (32, 16) remapped XCD-aware, block 256 (4 waves). Wave w owns 16 q-rows.
// QK^T computed transposed: D = K_tile . Q^T, so each lane holds 16 keys of ONE q-row.
// v5: XCD swizzle (all 64 blocks of a bh-pair on one XCD -> K/V/Q L2-resident);
// main loop unrolled x2 so the dbuf index is compile-time (hoisted swizzled addrs);
// row-sum L by ones-row MFMA; 2-tile-deep register prefetch; vote-based defer-max;
// in-kernel normalization writes merged bf16 Ab directly.
__global__ __launch_bounds__(256) void attn_kernel(const u16* __restrict__ Q,
                                                   const u16* __restrict__ K,
                                                   const u16* __restrict__ Vt,
                                                   const float* __restrict__ mask,
                                                   const int* __restrict__ flags,
                                                   u16* __restrict__ Ab) {
    const int tid = threadIdx.x;
    const int lane = tid & 63;
    const int wave = tid >> 6;
    const int cidx = lane & 15;   // q-row (QK^T B-operand col / PV B-col); d-row for V A-frag
    const int kg = lane >> 4;
    // XCD-aware remap: hw flat id round-robins XCDs; put blocks {8k+j} -> F=j*64+k so
    // XCD j gets F in [64j, 64j+64) = all 32 q-tiles of bh pair {2j, 2j+1}.
    const int flat = blockIdx.x + 32 * blockIdx.y;
    const int F = (flat & 7) * 64 + (flat >> 3);
    const int qt = F & 31;
    const int bh = F >> 5;
    const int b = bh >> 3, h = bh & 7;
    const int q0 = qt * 64 + wave * 16;

    __shared__ u16 kt_lds[2][64 * 64];   // [buf][key-local][dh], XOR-swizzled 8-blocks
    __shared__ u16 vt_lds[2][64 * 64];   // [buf][dh][key-local], XOR-swizzled
    __shared__ u16 p_lds[4][16 * 64];    // per-wave P^T as [q][key], XOR-swizzled
    u16* pw = p_lds[wave];

    // Q fragment: lane holds Q[q0+cidx][kg*8+j] (+32). Serves as B-operand of K.Q^T.
    const long qbase = ((long)(b * S_LEN + q0 + cidx)) * DMODEL + h * DHEAD + kg * 8;
    bf16x8 aq0 = ld8(Q + qbase);
    bf16x8 aq1 = ld8(Q + qbase + 32);

    // ones A-fragment: row 0 = 1.0, rows 1..15 = 0. mfma(ones, P^T) row 0 = sum_k P[q][k].
    bf16x8 onesf;
    {
        u16x8 t8;
        u16 ob = (cidx == 0) ? (u16)0x3F80 : (u16)0;
#pragma unroll
        for (int j = 0; j < 8; ++j) t8[j] = ob;
        onesf = *(bf16x8*)&t8;
    }

    const f32x4 fz = {0.f, 0.f, 0.f, 0.f};
    f32x4 acc[4];  // O^T accumulator: lane holds O[q0+cidx][16nt+4kg+r]
#pragma unroll
    for (int nt = 0; nt < 4; ++nt) acc[nt] = fz;
    f32x4 accL = fz;      // after ones-MFMA: lane q (kg==0), comp 0 holds running L[q]
    float mrow = -1e30f;  // per-lane: one q-row (log2 domain, deferred-max reference)

    // staging roles: 512 16B slots over 256 threads
    const int krow0 = tid >> 3, kseg0 = tid & 7;  // rows 0..31
    const int krow1 = krow0 + 32;                 // rows 32..63
    const u16* kgbase = K + ((long)(b * S_LEN)) * DMODEL + h * DHEAD;
    const u16* vgbase = Vt + ((long)bh * DHEAD) * S_LEN;
    const int kd0 = krow0 * 64 + (((kseg0 ^ (krow0 & 7))) << 3);
    const int kd1 = krow1 * 64 + (((kseg0 ^ (krow1 & 7))) << 3);
    const int* flagrow = flags + b * 1024 + qt * 32;
    const int NIT = S_LEN / 64;  // 32 (even -> clean x2 unroll)

    const u16* kp0 = kgbase + (long)krow0 * DMODEL + kseg0 * 8;
    const u16* kp1 = kgbase + (long)krow1 * DMODEL + kseg0 * 8;
    const u16* vp0 = vgbase + (long)krow0 * S_LEN + kseg0 * 8;
    const u16* vp1 = vgbase + (long)krow1 * S_LEN + kseg0 * 8;

    // prologue: tile 0 -> buf0, prefetch tile 1 into regs
    u16x8 rk0 = *(const u16x8*)kp0;
    u16x8 rk1 = *(const u16x8*)kp1;
    u16x8 rv0 = *(const u16x8*)vp0;
    u16x8 rv1 = *(const u16x8*)vp1;
    *(u16x8*)&kt_lds[0][kd0] = rk0;
    *(u16x8*)&kt_lds[0][kd1] = rk1;
    *(u16x8*)&vt_lds[0][kd0] = rv0;
    *(u16x8*)&vt_lds[0][kd1] = rv1;
    rk0 = *(const u16x8*)(kp0 + 64 * DMODEL);
    rk1 = *(const u16x8*)(kp1 + 64 * DMODEL);
    rv0 = *(const u16x8*)(vp0 + 64);
    rv1 = *(const u16x8*)(vp1 + 64);
    __syncthreads();

#define ATTN_TILE(IT, CUR)                                                                 \
    {                                                                                      \
        if ((IT) + 1 < NIT) {                                                              \
            u16* kn = kt_lds[(CUR) ^ 1];                                                   \
            u16* vn = vt_lds[(CUR) ^ 1];                                                   \
            *(u16x8*)&kn[kd0] = rk0;                                                       \
            *(u16x8*)&kn[kd1] = rk1;                                                       \
            *(u16x8*)&vn[kd0] = rv0;                                                       \
            *(u16x8*)&vn[kd1] = rv1;                                                       \
            if ((IT) + 2 < NIT) {                                                          \
                const int t2 = ((IT) + 2) * 64;                                            \
                rk0 = *(const u16x8*)(kp0 + (long)t2 * DMODEL);                            \
                rk1 = *(const u16x8*)(kp1 + (long)t2 * DMODEL);                            \
                rv0 = *(const u16x8*)(vp0 + t2);                                           \
                rv1 = *(const u16x8*)(vp1 + t2);                                           \
            }                                                                              \
        }                                                                                  \
        const int flg = flagrow[(IT)];                                                     \
        const u16* kb = kt_lds[(CUR)];                                                     \
        const u16* vb = vt_lds[(CUR)];                                                     \
        f32x4 sacc[4];                                                                     \
        _Pragma("unroll")                                                                  \
        for (int ct = 0; ct < 4; ++ct) sacc[ct] = fz;                                      \
        __builtin_amdgcn_s_setprio(1);                                                     \
        _Pragma("unroll")                                                                  \
        for (int ct = 0; ct < 4; ++ct) {                                                   \
            int r = ct * 16 + cidx;                                                        \
            bf16x8 kv0 = ld8(&kb[r * 64 + ((kg ^ (r & 7)) << 3)]);                         \
            bf16x8 kv1 = ld8(&kb[r * 64 + (((4 ^ kg) ^ (r & 7)) << 3)]);                   \
            sacc[ct] = __builtin_amdgcn_mfma_f32_16x16x32_bf16(kv0, aq0, sacc[ct], 0, 0, 0); \
            sacc[ct] = __builtin_amdgcn_mfma_f32_16x16x32_bf16(kv1, aq1, sacc[ct], 0, 0, 0); \
        }                                                                                  \
        __builtin_amdgcn_s_setprio(0);                                                     \
        if (flg) {                                                                         \
            const float* mb = mask + ((long)(b * S_LEN + q0 + cidx)) * S_LEN + (IT) * 64 + kg * 4; \
            _Pragma("unroll")                                                              \
            for (int ct = 0; ct < 4; ++ct) {                                               \
                f32x4 mv = *(const f32x4*)(mb + ct * 16);                                  \
                _Pragma("unroll")                                                          \
                for (int r = 0; r < 4; ++r) sacc[ct][r] -= MASKC * mv[r];                  \
            }                                                                              \
        }                                                                                  \
        float t0 = fmax3(sacc[0][0], sacc[0][1], sacc[0][2]);                              \
        float t1 = fmax3(sacc[0][3], sacc[1][0], sacc[1][1]);                              \
        float t2 = fmax3(sacc[1][2], sacc[1][3], sacc[2][0]);                              \
        float t3 = fmax3(sacc[2][1], sacc[2][2], sacc[2][3]);                              \
        float t4 = fmax3(sacc[3][0], sacc[3][1], sacc[3][2]);                              \
        float mxl = __builtin_fmaxf(fmax3(fmax3(t0, t1, t2), t3, t4), sacc[3][3]);         \
        if (__any(mxl > mrow + RESCALE_THR)) {                                             \
            float mx = fmaxf(mxl, __shfl_xor(mxl, 16));                                    \
            mx = fmaxf(mx, __shfl_xor(mx, 32));                                            \
            float mnew = fmaxf(mrow, mx);                                                  \
            float alpha = __builtin_amdgcn_exp2f(mrow - mnew);                             \
            mrow = mnew;                                                                   \
            accL = accL * alpha;                                                           \
            _Pragma("unroll")                                                              \
            for (int nt = 0; nt < 4; ++nt) acc[nt] = acc[nt] * alpha;                      \
        }                                                                                  \
        _Pragma("unroll")                                                                  \
        for (int ct = 0; ct < 4; ++ct)                                                     \
            _Pragma("unroll")                                                              \
            for (int r = 0; r < 4; ++r)                                                    \
                sacc[ct][r] = __builtin_amdgcn_exp2f(sacc[ct][r] - mrow);                  \
        _Pragma("unroll")                                                                  \
        for (int ct = 0; ct < 4; ++ct) {                                                   \
            u32x2 d;                                                                       \
            d[0] = pk2bf(sacc[ct][0], sacc[ct][1]);                                        \
            d[1] = pk2bf(sacc[ct][2], sacc[ct][3]);                                        \
            int blk = 2 * ct + (kg >> 1);                                                  \
            *(u32x2*)&pw[cidx * 64 + ((blk ^ (cidx & 7)) << 3) + (kg & 1) * 4] = d;        \
        }                                                                                  \
        bf16x8 pf0 = ld8(&pw[cidx * 64 + ((kg ^ (cidx & 7)) << 3)]);                       \
        bf16x8 pf1 = ld8(&pw[cidx * 64 + (((4 ^ kg) ^ (cidx & 7)) << 3)]);                 \
        __builtin_amdgcn_s_setprio(1);                                                     \
        _Pragma("unroll")                                                                  \
        for (int nt = 0; nt < 4; ++nt) {                                                   \
            int rr = nt * 16 + cidx;                                                       \
            bf16x8 v0 = ld8(&vb[rr * 64 + ((kg ^ (rr & 7)) << 3)]);                        \
            bf16x8 v1 = ld8(&vb[rr * 64 + (((4 ^ kg) ^ (rr & 7)) << 3)]);                  \
            acc[nt] = __builtin_amdgcn_mfma_f32_16x16x32_bf16(v0, pf0, acc[nt], 0, 0, 0);  \
            acc[nt] = __builtin_amdgcn_mfma_f32_16x16x32_bf16(v1, pf1, acc[nt], 0, 0, 0);  \
        }                                                                                  \
        accL = __builtin_amdgcn_mfma_f32_16x16x32_bf16(onesf, pf0, accL, 0, 0, 0);         \
        accL = __builtin_amdgcn_mfma_f32_16x16x32_bf16(onesf, pf1, accL, 0, 0, 0);         \
        __builtin_amdgcn_s_setprio(0);                                                     \
        __syncthreads();                                                                   \
    }

    for (int it = 0; it < NIT; it += 2) {
        ATTN_TILE(it, 0)
        ATTN_TILE(it + 1, 1)
    }
#undef ATTN_TILE

    // epilogue: L[q] sits in lane q (kg==0), comp 0 — broadcast, normalize, write bf16 Ab.
    float Lb = __shfl(accL[0], cidx);
    float invL = 1.f / Lb;
    const long abase = ((long)(b * S_LEN + q0 + cidx)) * DMODEL + h * DHEAD;
#pragma unroll
    for (int nt = 0; nt < 4; ++nt) {
        u32x2 d;
        d[0] = pk2bf(acc[nt][0] * invL, acc[nt][1] * invL);
        d[1] = pk2bf(acc[nt][2] * invL, acc[nt][3] * invL);
        *(u32x2*)(Ab + abase + nt * 16 + kg * 4) = d;
    }
}

extern "C" void kernel_launch(void* const* d_in, const int* in_sizes, int n_in,
                              void* d_out, int out_size, void* d_ws, size_t ws_size,
                              hipStream_t stream) {
    const float* q_in = (const float*)d_in[0];
    const float* k_in = (const float*)d_in[1];
    const float* v_in = (const float*)d_in[2];
    const float* mask = (const float*)d_in[3];
    const float* wq = (const float*)d_in[4];
    const float* bq = (const float*)d_in[5];
    const float* wk = (const float*)d_in[6];
    const float* bk = (const float*)d_in[7];
    const float* wv = (const float*)d_in[8];
    const float* bv = (const float*)d_in[9];
    const float* wo = (const float*)d_in[10];
    const float* bo = (const float*)d_in[11];

    // ws layout (u16 units):
    u16* ws = (u16*)d_ws;
    u16* Qb = ws;                       // 2.1M  projected Q (pre-scaled QSCALE)
    u16* Kb = Qb + 2097152;             // 2.1M
    u16* Vt = Kb + 2097152;             // 2.1M  V transposed (B,H,DH,S) - written by qkv_gemm
    u16* wtall = Vt + 2097152;          // 4 x 262144: [wo, wq, wk, wv]
    u16* Ab = wtall + 4 * 262144;       // 2.1M  attention output (merged heads)
    int* mflags = (int*)(Ab + 2097152); // 2048 ints

    prep_kernel<<<3072, 256, 0, stream>>>(wq, wk, wv, wo, mask, wtall, mflags);
    qkv_gemm_kernel<<<dim3(8, 32, 3), 256, 0, stream>>>(q_in, k_in, v_in, wtall,
                                                        bq, bk, bv, Qb, Kb, Vt);
    attn_kernel<<<dim3(32, 16), 256, 0, stream>>>(Qb, Kb, Vt, mask, mflags, Ab);
    out_gemm_kernel<<<dim3(8, 64), 256, 0, stream>>>(Ab, wtall, bo, (float*)d_out);
}

// Round 6
// 219.110 us; speedup vs baseline: 1.0222x; 1.0222x over previous
//
#include <hip/hip_runtime.h>
#include <hip/hip_bf16.h>

typedef unsigned short u16;
typedef unsigned int u32;
typedef __bf16 bf16x8 __attribute__((ext_vector_type(8)));
typedef float f32x4 __attribute__((ext_vector_type(4)));
typedef u16 u16x8 __attribute__((ext_vector_type(8)));
typedef u32 u32x2 __attribute__((ext_vector_type(2)));

#define S_LEN 2048
#define DMODEL 512
#define NHEAD 8
#define DHEAD 64
// log2(e); Q is pre-scaled by 0.125*LOG2E so softmax runs in exp2 domain.
#define QSCALE 0.1803368801111204f
#define MASKC 1.4426950409e9f
#define RESCALE_THR 8.0f

static __device__ __forceinline__ u16 f2bf(float f) {
    union { float f; unsigned u; } cv; cv.f = f;
    unsigned u = cv.u;
    return (u16)((u + 0x7fffu + ((u >> 16) & 1u)) >> 16);  // RNE
}
static __device__ __forceinline__ u32 pk2bf(float a, float b) {
    union { __hip_bfloat162 h; u32 u; } cv;
    float2 f2; f2.x = a; f2.y = b;
    cv.h = __float22bfloat162_rn(f2);
    return cv.u;
}
static __device__ __forceinline__ bf16x8 ld8(const u16* p) {
    return *(const bf16x8*)p;
}
static __device__ __forceinline__ float fmax3(float a, float b, float c) {
    return __builtin_fmaxf(__builtin_fmaxf(a, b), c);  // clang fuses to v_max3_f32
}

// ---------------- fused prep: qkv fp32->bf16 cvt | weight transpose->bf16 | mask flags ----
// grid.x partition: [0,3072) cvt, [3072,4096) transpose_w, [4096,6144) mask flags. 256 thr.
__global__ __launch_bounds__(256) void prep_kernel(
    const float* __restrict__ q, const float* __restrict__ k, const float* __restrict__ v,
    const float* __restrict__ w0, const float* __restrict__ w1,
    const float* __restrict__ w2, const float* __restrict__ w3,
    const float* __restrict__ mask,
    u16* __restrict__ Aqkv, u16* __restrict__ wtall, int* __restrict__ flags) {
    const int p = blockIdx.x;
    const int tid = threadIdx.x;
    __shared__ float t[32][33];
    __shared__ int wred[4];
    if (p < 3072) {
        const int z = p >> 10, px = p & 1023;
        const float* in = (z == 0) ? q : (z == 1) ? k : v;
        u16* o = Aqkv + (long)z * 2097152;
        long i = ((long)px * 256 + tid) * 8;
        f32x4 a = *(const f32x4*)(in + i);
        f32x4 b = *(const f32x4*)(in + i + 4);
        u16x8 r;
#pragma unroll
        for (int j = 0; j < 4; ++j) { r[j] = f2bf(a[j]); r[4 + j] = f2bf(b[j]); }
        *(u16x8*)(o + i) = r;
    } else if (p < 4096) {
        // W (512x512 fp32) -> Wt bf16 (N x K). slot order in wtall: [wo, wq, wk, wv]
        const int p2 = p - 3072;
        const int z = p2 >> 8, rem = p2 & 255, by = rem >> 4, bx = rem & 15;
        const float* in = (z == 0) ? w0 : (z == 1) ? w1 : (z == 2) ? w2 : w3;
        u16* o = wtall + (long)(((z + 1) & 3)) * 262144;
        const int tx = tid & 31, ty = tid >> 5;
#pragma unroll
        for (int i = 0; i < 4; ++i)
            t[ty + 8 * i][tx] = in[(by * 32 + ty + 8 * i) * DMODEL + bx * 32 + tx];
        __syncthreads();
#pragma unroll
        for (int i = 0; i < 4; ++i)
            o[(bx * 32 + ty + 8 * i) * DMODEL + by * 32 + tx] = f2bf(t[tx][ty + 8 * i]);
    } else {
        const int bid = p - 4096;  // 2*32*32
        const int b = bid >> 10, qt = (bid >> 5) & 31, kt = bid & 31;
        const int r = tid >> 2, cs = tid & 3;
        const float* mp = mask + ((long)(b * S_LEN + qt * 64 + r)) * S_LEN + kt * 64 + cs * 16;
        int nz = 0;
#pragma unroll
        for (int j = 0; j < 4; ++j) {
            f32x4 a = *(const f32x4*)(mp + j * 4);
            nz |= (a[0] != 0.f) | (a[1] != 0.f) | (a[2] != 0.f) | (a[3] != 0.f);
        }
        unsigned long long ball = __ballot(nz);
        if ((tid & 63) == 0) wred[tid >> 6] = (ball != 0ull) ? 1 : 0;
        __syncthreads();
        if (tid == 0) flags[bid] = wred[0] | wred[1] | wred[2] | wred[3];
    }
}

// ---------------- GEMM: C(4096x512) = A(4096x512) @ W + bias; block tile (TM*32) x 64,
// 4 waves (2x2), wave tile (TM*16) x 32. bx/by are pre-swizzled (XCD-aware) tile indices.
// vtout: write C transposed per head into Vt (B,H,DH,S) with packed 8B stores.
template <bool F32OUT, int TM>
static __device__ __forceinline__ void gemm_body(const u16* __restrict__ A,
                                                 const u16* __restrict__ Wt,
                                                 const float* __restrict__ bias,
                                                 void* __restrict__ Cp, float oscale,
                                                 bool vtout, int bx, int by) {
    const int lane = threadIdx.x & 63;
    const int wave = threadIdx.x >> 6;
    const int wr = wave >> 1, wc = wave & 1;
    const int m0 = by * (TM * 32) + wr * (TM * 16);
    const int n0 = bx * 64 + wc * 32;
    const int cidx = lane & 15;
    const int kg = lane >> 4;

    const u16* aptr[TM];
    const u16* bptr[2];
#pragma unroll
    for (int t = 0; t < TM; ++t)
        aptr[t] = A + (long)(m0 + t * 16 + cidx) * DMODEL + kg * 8;
#pragma unroll
    for (int t = 0; t < 2; ++t)
        bptr[t] = Wt + (long)(n0 + t * 16 + cidx) * DMODEL + kg * 8;

    const f32x4 fz = {0.f, 0.f, 0.f, 0.f};
    f32x4 acc[TM][2];
#pragma unroll
    for (int i = 0; i < TM; ++i)
#pragma unroll
        for (int j = 0; j < 2; ++j) acc[i][j] = fz;

#pragma unroll 4
    for (int k0 = 0; k0 < 512; k0 += 32) {
        bf16x8 a[TM], b[2];
#pragma unroll
        for (int t = 0; t < TM; ++t) a[t] = ld8(aptr[t] + k0);
#pragma unroll
        for (int t = 0; t < 2; ++t) b[t] = ld8(bptr[t] + k0);
#pragma unroll
        for (int i = 0; i < TM; ++i)
#pragma unroll
            for (int j = 0; j < 2; ++j)
                acc[i][j] = __builtin_amdgcn_mfma_f32_16x16x32_bf16(a[i], b[j], acc[i][j], 0, 0, 0);
    }

    if (vtout) {
        // V-transposed epilogue: row = token (b, s), col = channel (h, d).
        // Lane's 4 acc rows are consecutive tokens at fixed d -> one packed 8B store.
        const int bb = m0 >> 11;  // batch (tile never crosses the 2048 boundary)
#pragma unroll
        for (int j = 0; j < 2; ++j) {
            int col = n0 + j * 16 + cidx;
            float bv = bias[col];
            u16* vt = (u16*)Cp + (((long)(bb * 8 + (col >> 6))) * 64 + (col & 63)) * S_LEN;
#pragma unroll
            for (int i = 0; i < TM; ++i) {
                int s = (m0 + i * 16 + kg * 4) & (S_LEN - 1);
                u32x2 d;
                d[0] = pk2bf(acc[i][j][0] + bv, acc[i][j][1] + bv);
                d[1] = pk2bf(acc[i][j][2] + bv, acc[i][j][3] + bv);
                *(u32x2*)(vt + s) = d;
            }
        }
        return;
    }

#pragma unroll
    for (int j = 0; j < 2; ++j) {
        int col = n0 + j * 16 + cidx;
        float bv = bias[col];
#pragma unroll
        for (int i = 0; i < TM; ++i) {
#pragma unroll
            for (int r = 0; r < 4; ++r) {
                int row = m0 + i * 16 + kg * 4 + r;
                float val = (acc[i][j][r] + bv) * oscale;
                if (F32OUT) {
                    ((float*)Cp)[(long)row * DMODEL + col] = val;
                } else {
                    ((u16*)Cp)[(long)row * DMODEL + col] = f2bf(val);
                }
            }
        }
    }
}

// XCD-aware swizzle (T1): dispatch order round-robins XCDs; remap so the 8 bx-blocks
// sharing one A row-panel all land on ONE XCD -> A panel fetched into that L2 once.
// Requires gridY % 8 == 0. Bijective: (xcd, j) <-> flat.
static __device__ __forceinline__ void xcd_swizzle(int gridX, int gridY, int& bx, int& by) {
    const int flat = blockIdx.x + gridX * blockIdx.y;
    const int xcd = flat & 7;
    const int j = flat >> 3;
    by = xcd * (gridY >> 3) + j / gridX;
    bx = j % gridX;
}

// qkv: 64x64 block tile (TM=2) -> grid (8,64,3) = 1536 blocks = 6/CU (latency hiding).
__global__ __launch_bounds__(256) void qkv_gemm_kernel(
    const u16* __restrict__ Aqkv,
    const u16* __restrict__ wtall,
    const float* __restrict__ bq, const float* __restrict__ bk, const float* __restrict__ bv,
    u16* __restrict__ Q, u16* __restrict__ K, u16* __restrict__ Vt) {
    const u16* A = Aqkv + (long)blockIdx.z * 2097152;
    const u16* W = wtall + (long)(blockIdx.z + 1) * 262144;  // [wo, wq, wk, wv]
    const float* b;
    u16* C;
    float sc = 1.f;
    bool vt = false;
    if (blockIdx.z == 0) { b = bq; C = Q; sc = QSCALE; }  // fold 1/sqrt(DH)*log2e into Q
    else if (blockIdx.z == 1) { b = bk; C = K; }
    else { b = bv; C = Vt; vt = true; }
    int bx, by;
    xcd_swizzle(8, 64, bx, by);
    gemm_body<false, 2>(A, W, b, C, sc, vt, bx, by);
}

__global__ __launch_bounds__(256) void out_gemm_kernel(const u16* __restrict__ A,
                                                       const u16* __restrict__ Wt,
                                                       const float* __restrict__ bias,
                                                       float* __restrict__ C) {
    int bx, by;
    xcd_swizzle(8, 64, bx, by);
    gemm_body<true, 2>(A, Wt, bias, C, 1.f, false, bx, by);
}

// ---------------- flash attention, S^T formulation ----------------
// grid: (32, 16) remapped XCD-aware, block 256 (4 waves). Wave w owns 16 q-rows.
// QK^T computed transposed: D = K_tile . Q^T, so each lane holds 16 keys of ONE q-row.
// XCD swizzle (all 64 blocks of a bh-pair on one XCD -> K/V/Q L2-resident);
// main loop unrolled x2 so the dbuf index is compile-time (hoisted swizzled addrs);
// row-sum L by ones-row MFMA; 2-tile-deep register prefetch; vote-based defer-max;
// in-kernel normalization writes merged bf16 Ab directly.
__global__ __launch_bounds__(256) void attn_kernel(const u16* __restrict__ Q,
                                                   const u16* __restrict__ K,
                                                   const u16* __restrict__ Vt,
                                                   const float* __restrict__ mask,
                                                   const int* __restrict__ flags,
                                                   u16* __restrict__ Ab) {
    const int tid = threadIdx.x;
    const int lane = tid & 63;
    const int wave = tid >> 6;
    const int cidx = lane & 15;   // q-row (QK^T B-operand col / PV B-col); d-row for V A-frag
    const int kg = lane >> 4;
    // XCD-aware remap: hw flat id round-robins XCDs; put blocks {8k+j} -> F=j*64+k so
    // XCD j gets F in [64j, 64j+64) = all 32 q-tiles of bh pair {2j, 2j+1}.
    const int flat = blockIdx.x + 32 * blockIdx.y;
    const int F = (flat & 7) * 64 + (flat >> 3);
    const int qt = F & 31;
    const int bh = F >> 5;
    const int b = bh >> 3, h = bh & 7;
    const int q0 = qt * 64 + wave * 16;

    __shared__ u16 kt_lds[2][64 * 64];   // [buf][key-local][dh], XOR-swizzled 8-blocks
    __shared__ u16 vt_lds[2][64 * 64];   // [buf][dh][key-local], XOR-swizzled
    __shared__ u16 p_lds[4][16 * 64];    // per-wave P^T as [q][key], XOR-swizzled
    u16* pw = p_lds[wave];

    // Q fragment: lane holds Q[q0+cidx][kg*8+j] (+32). Serves as B-operand of K.Q^T.
    const long qbase = ((long)(b * S_LEN + q0 + cidx)) * DMODEL + h * DHEAD + kg * 8;
    bf16x8 aq0 = ld8(Q + qbase);
    bf16x8 aq1 = ld8(Q + qbase + 32);

    // ones A-fragment: row 0 = 1.0, rows 1..15 = 0. mfma(ones, P^T) row 0 = sum_k P[q][k].
    bf16x8 onesf;
    {
        u16x8 t8;
        u16 ob = (cidx == 0) ? (u16)0x3F80 : (u16)0;
#pragma unroll
        for (int j = 0; j < 8; ++j) t8[j] = ob;
        onesf = *(bf16x8*)&t8;
    }

    const f32x4 fz = {0.f, 0.f, 0.f, 0.f};
    f32x4 acc[4];  // O^T accumulator: lane holds O[q0+cidx][16nt+4kg+r]
#pragma unroll
    for (int nt = 0; nt < 4; ++nt) acc[nt] = fz;
    f32x4 accL = fz;      // after ones-MFMA: lane q (kg==0), comp 0 holds running L[q]
    float mrow = -1e30f;  // per-lane: one q-row (log2 domain, deferred-max reference)

    // staging roles: 512 16B slots over 256 threads
    const int krow0 = tid >> 3, kseg0 = tid & 7;  // rows 0..31
    const int krow1 = krow0 + 32;                 // rows 32..63
    const u16* kgbase = K + ((long)(b * S_LEN)) * DMODEL + h * DHEAD;
    const u16* vgbase = Vt + ((long)bh * DHEAD) * S_LEN;
    const int kd0 = krow0 * 64 + (((kseg0 ^ (krow0 & 7))) << 3);
    const int kd1 = krow1 * 64 + (((kseg0 ^ (krow1 & 7))) << 3);
    const int* flagrow = flags + b * 1024 + qt * 32;
    const int NIT = S_LEN / 64;  // 32 (even -> clean x2 unroll)

    const u16* kp0 = kgbase + (long)krow0 * DMODEL + kseg0 * 8;
    const u16* kp1 = kgbase + (long)krow1 * DMODEL + kseg0 * 8;
    const u16* vp0 = vgbase + (long)krow0 * S_LEN + kseg0 * 8;
    const u16* vp1 = vgbase + (long)krow1 * S_LEN + kseg0 * 8;

    // prologue: tile 0 -> buf0, prefetch tile 1 into regs
    u16x8 rk0 = *(const u16x8*)kp0;
    u16x8 rk1 = *(const u16x8*)kp1;
    u16x8 rv0 = *(const u16x8*)vp0;
    u16x8 rv1 = *(const u16x8*)vp1;
    *(u16x8*)&kt_lds[0][kd0] = rk0;
    *(u16x8*)&kt_lds[0][kd1] = rk1;
    *(u16x8*)&vt_lds[0][kd0] = rv0;
    *(u16x8*)&vt_lds[0][kd1] = rv1;
    rk0 = *(const u16x8*)(kp0 + 64 * DMODEL);
    rk1 = *(const u16x8*)(kp1 + 64 * DMODEL);
    rv0 = *(const u16x8*)(vp0 + 64);
    rv1 = *(const u16x8*)(vp1 + 64);
    __syncthreads();

#define ATTN_TILE(IT, CUR)                                                                 \
    {                                                                                      \
        if ((IT) + 1 < NIT) {                                                              \
            u16* kn = kt_lds[(CUR) ^ 1];                                                   \
            u16* vn = vt_lds[(CUR) ^ 1];                                                   \
            *(u16x8*)&kn[kd0] = rk0;                                                       \
            *(u16x8*)&kn[kd1] = rk1;                                                       \
            *(u16x8*)&vn[kd0] = rv0;                                                       \
            *(u16x8*)&vn[kd1] = rv1;                                                       \
            if ((IT) + 2 < NIT) {                                                          \
                const int t2 = ((IT) + 2) * 64;                                            \
                rk0 = *(const u16x8*)(kp0 + (long)t2 * DMODEL);                            \
                rk1 = *(const u16x8*)(kp1 + (long)t2 * DMODEL);                            \
                rv0 = *(const u16x8*)(vp0 + t2);                                           \
                rv1 = *(const u16x8*)(vp1 + t2);                                           \
            }                                                                              \
        }                                                                                  \
        const int flg = flagrow[(IT)];                                                     \
        const u16* kb = kt_lds[(CUR)];                                                     \
        const u16* vb = vt_lds[(CUR)];                                                     \
        f32x4 sacc[4];                                                                     \
        _Pragma("unroll")                                                                  \
        for (int ct = 0; ct < 4; ++ct) sacc[ct] = fz;                                      \
        __builtin_amdgcn_s_setprio(1);                                                     \
        _Pragma("unroll")                                                                  \
        for (int ct = 0; ct < 4; ++ct) {                                                   \
            int r = ct * 16 + cidx;                                                        \
            bf16x8 kv0 = ld8(&kb[r * 64 + ((kg ^ (r & 7)) << 3)]);                         \
            bf16x8 kv1 = ld8(&kb[r * 64 + (((4 ^ kg) ^ (r & 7)) << 3)]);                   \
            sacc[ct] = __builtin_amdgcn_mfma_f32_16x16x32_bf16(kv0, aq0, sacc[ct], 0, 0, 0); \
            sacc[ct] = __builtin_amdgcn_mfma_f32_16x16x32_bf16(kv1, aq1, sacc[ct], 0, 0, 0); \
        }                                                                                  \
        __builtin_amdgcn_s_setprio(0);                                                     \
        if (flg) {                                                                         \
            const float* mb = mask + ((long)(b * S_LEN + q0 + cidx)) * S_LEN + (IT) * 64 + kg * 4; \
            _Pragma("unroll")                                                              \
            for (int ct = 0; ct < 4; ++ct) {                                               \
                f32x4 mv = *(const f32x4*)(mb + ct * 16);                                  \
                _Pragma("unroll")                                                          \
                for (int r = 0; r < 4; ++r) sacc[ct][r] -= MASKC * mv[r];                  \
            }                                                                              \
        }                                                                                  \
        float t0 = fmax3(sacc[0][0], sacc[0][1], sacc[0][2]);                              \
        float t1 = fmax3(sacc[0][3], sacc[1][0], sacc[1][1]);                              \
        float t2 = fmax3(sacc[1][2], sacc[1][3], sacc[2][0]);                              \
        float t3 = fmax3(sacc[2][1], sacc[2][2], sacc[2][3]);                              \
        float t4 = fmax3(sacc[3][0], sacc[3][1], sacc[3][2]);                              \
        float mxl = __builtin_fmaxf(fmax3(fmax3(t0, t1, t2), t3, t4), sacc[3][3]);         \
        if (__any(mxl > mrow + RESCALE_THR)) {                                             \
            float mx = fmaxf(mxl, __shfl_xor(mxl, 16));                                    \
            mx = fmaxf(mx, __shfl_xor(mx, 32));                                            \
            float mnew = fmaxf(mrow, mx);                                                  \
            float alpha = __builtin_amdgcn_exp2f(mrow - mnew);                             \
            mrow = mnew;                                                                   \
            accL = accL * alpha;                                                           \
            _Pragma("unroll")                                                              \
            for (int nt = 0; nt < 4; ++nt) acc[nt] = acc[nt] * alpha;                      \
        }                                                                                  \
        _Pragma("unroll")                                                                  \
        for (int ct = 0; ct < 4; ++ct)                                                     \
            _Pragma("unroll")                                                              \
            for (int r = 0; r < 4; ++r)                                                    \
                sacc[ct][r] = __builtin_amdgcn_exp2f(sacc[ct][r] - mrow);                  \
        _Pragma("unroll")                                                                  \
        for (int ct = 0; ct < 4; ++ct) {                                                   \
            u32x2 d;                                                                       \
            d[0] = pk2bf(sacc[ct][0], sacc[ct][1]);                                        \
            d[1] = pk2bf(sacc[ct][2], sacc[ct][3]);                                        \
            int blk = 2 * ct + (kg >> 1);                                                  \
            *(u32x2*)&pw[cidx * 64 + ((blk ^ (cidx & 7)) << 3) + (kg & 1) * 4] = d;        \
        }                                                                                  \
        bf16x8 pf0 = ld8(&pw[cidx * 64 + ((kg ^ (cidx & 7)) << 3)]);                       \
        bf16x8 pf1 = ld8(&pw[cidx * 64 + (((4 ^ kg) ^ (cidx & 7)) << 3)]);                 \
        __builtin_amdgcn_s_setprio(1);                                                     \
        _Pragma("unroll")                                                                  \
        for (int nt = 0; nt < 4; ++nt) {                                                   \
            int rr = nt * 16 + cidx;                                                       \
            bf16x8 v0 = ld8(&vb[rr * 64 + ((kg ^ (rr & 7)) << 3)]);                        \
            bf16x8 v1 = ld8(&vb[rr * 64 + (((4 ^ kg) ^ (rr & 7)) << 3)]);                  \
            acc[nt] = __builtin_amdgcn_mfma_f32_16x16x32_bf16(v0, pf0, acc[nt], 0, 0, 0);  \
            acc[nt] = __builtin_amdgcn_mfma_f32_16x16x32_bf16(v1, pf1, acc[nt], 0, 0, 0);  \
        }                                                                                  \
        accL = __builtin_amdgcn_mfma_f32_16x16x32_bf16(onesf, pf0, accL, 0, 0, 0);         \
        accL = __builtin_amdgcn_mfma_f32_16x16x32_bf16(onesf, pf1, accL, 0, 0, 0);         \
        __builtin_amdgcn_s_setprio(0);                                                     \
        __syncthreads();                                                                   \
    }

    for (int it = 0; it < NIT; it += 2) {
        ATTN_TILE(it, 0)
        ATTN_TILE(it + 1, 1)
    }
#undef ATTN_TILE

    // epilogue: L[q] sits in lane q (kg==0), comp 0 — broadcast, normalize, write bf16 Ab.
    float Lb = __shfl(accL[0], cidx);
    float invL = 1.f / Lb;
    const long abase = ((long)(b * S_LEN + q0 + cidx)) * DMODEL + h * DHEAD;
#pragma unroll
    for (int nt = 0; nt < 4; ++nt) {
        u32x2 d;
        d[0] = pk2bf(acc[nt][0] * invL, acc[nt][1] * invL);
        d[1] = pk2bf(acc[nt][2] * invL, acc[nt][3] * invL);
        *(u32x2*)(Ab + abase + nt * 16 + kg * 4) = d;
    }
}

extern "C" void kernel_launch(void* const* d_in, const int* in_sizes, int n_in,
                              void* d_out, int out_size, void* d_ws, size_t ws_size,
                              hipStream_t stream) {
    const float* q_in = (const float*)d_in[0];
    const float* k_in = (const float*)d_in[1];
    const float* v_in = (const float*)d_in[2];
    const float* mask = (const float*)d_in[3];
    const float* wq = (const float*)d_in[4];
    const float* bq = (const float*)d_in[5];
    const float* wk = (const float*)d_in[6];
    const float* bk = (const float*)d_in[7];
    const float* wv = (const float*)d_in[8];
    const float* bv = (const float*)d_in[9];
    const float* wo = (const float*)d_in[10];
    const float* bo = (const float*)d_in[11];

    // ws layout (u16 units):
    u16* ws = (u16*)d_ws;
    u16* Qb = ws;                       // 2.1M  projected Q (pre-scaled QSCALE)
    u16* Kb = Qb + 2097152;             // 2.1M
    u16* Vt = Kb + 2097152;             // 2.1M  V transposed (B,H,DH,S) - written by qkv_gemm
    u16* wtall = Vt + 2097152;          // 4 x 262144: [wo, wq, wk, wv]
    u16* Sreg = wtall + 4 * 262144;     // 3 x 2.1M: Aq,Ak,Av  (dead after qkv_gemm)
    u16* Ab = Sreg + 3 * 2097152;       // 2.1M  attention output (merged heads)
    int* mflags = (int*)(Ab + 2097152); // 2048 ints

    prep_kernel<<<6144, 256, 0, stream>>>(q_in, k_in, v_in, wq, wk, wv, wo, mask,
                                          Sreg, wtall, mflags);
    qkv_gemm_kernel<<<dim3(8, 64, 3), 256, 0, stream>>>(Sreg, wtall, bq, bk, bv, Qb, Kb, Vt);
    attn_kernel<<<dim3(32, 16), 256, 0, stream>>>(Qb, Kb, Vt, mask, mflags, Ab);
    out_gemm_kernel<<<dim3(8, 64), 256, 0, stream>>>(Ab, wtall, bo, (float*)d_out);
}

// Round 7
// 171.178 us; speedup vs baseline: 1.3085x; 1.2800x over previous
//
#include <hip/hip_runtime.h>
#include <hip/hip_bf16.h>

typedef unsigned short u16;
typedef unsigned int u32;
typedef __bf16 bf16x8 __attribute__((ext_vector_type(8)));
typedef float f32x4 __attribute__((ext_vector_type(4)));
typedef u16 u16x8 __attribute__((ext_vector_type(8)));
typedef u32 u32x2 __attribute__((ext_vector_type(2)));

#define S_LEN 2048
#define DMODEL 512
#define NHEAD 8
#define DHEAD 64
// log2(e); Q is pre-scaled by 0.125*LOG2E so softmax runs in exp2 domain.
#define QSCALE 0.1803368801111204f
#define MASKC 1.4426950409e9f
#define RESCALE_THR 8.0f

static __device__ __forceinline__ u16 f2bf(float f) {
    union { float f; unsigned u; } cv; cv.f = f;
    unsigned u = cv.u;
    return (u16)((u + 0x7fffu + ((u >> 16) & 1u)) >> 16);  // RNE
}
static __device__ __forceinline__ u32 pk2bf(float a, float b) {
    union { __hip_bfloat162 h; u32 u; } cv;
    float2 f2; f2.x = a; f2.y = b;
    cv.h = __float22bfloat162_rn(f2);
    return cv.u;
}
static __device__ __forceinline__ bf16x8 ld8(const u16* p) {
    return *(const bf16x8*)p;
}
static __device__ __forceinline__ float fmax3(float a, float b, float c) {
    return __builtin_fmaxf(__builtin_fmaxf(a, b), c);  // clang fuses to v_max3_f32
}

// ---------------- fused prep: qkv fp32->bf16 cvt | weight transpose->bf16 | mask flags ----
// grid.x partition: [0,3072) cvt, [3072,4096) transpose_w, [4096,6144) mask flags. 256 thr.
__global__ __launch_bounds__(256) void prep_kernel(
    const float* __restrict__ q, const float* __restrict__ k, const float* __restrict__ v,
    const float* __restrict__ w0, const float* __restrict__ w1,
    const float* __restrict__ w2, const float* __restrict__ w3,
    const float* __restrict__ mask,
    u16* __restrict__ Aqkv, u16* __restrict__ wtall, int* __restrict__ flags) {
    const int p = blockIdx.x;
    const int tid = threadIdx.x;
    __shared__ float t[32][33];
    __shared__ int wred[4];
    if (p < 3072) {
        const int z = p >> 10, px = p & 1023;
        const float* in = (z == 0) ? q : (z == 1) ? k : v;
        u16* o = Aqkv + (long)z * 2097152;
        long i = ((long)px * 256 + tid) * 8;
        f32x4 a = *(const f32x4*)(in + i);
        f32x4 b = *(const f32x4*)(in + i + 4);
        u16x8 r;
#pragma unroll
        for (int j = 0; j < 4; ++j) { r[j] = f2bf(a[j]); r[4 + j] = f2bf(b[j]); }
        *(u16x8*)(o + i) = r;
    } else if (p < 4096) {
        // W (512x512 fp32) -> Wt bf16 (N x K). slot order in wtall: [wo, wq, wk, wv]
        const int p2 = p - 3072;
        const int z = p2 >> 8, rem = p2 & 255, by = rem >> 4, bx = rem & 15;
        const float* in = (z == 0) ? w0 : (z == 1) ? w1 : (z == 2) ? w2 : w3;
        u16* o = wtall + (long)(((z + 1) & 3)) * 262144;
        const int tx = tid & 31, ty = tid >> 5;
#pragma unroll
        for (int i = 0; i < 4; ++i)
            t[ty + 8 * i][tx] = in[(by * 32 + ty + 8 * i) * DMODEL + bx * 32 + tx];
        __syncthreads();
#pragma unroll
        for (int i = 0; i < 4; ++i)
            o[(bx * 32 + ty + 8 * i) * DMODEL + by * 32 + tx] = f2bf(t[tx][ty + 8 * i]);
    } else {
        const int bid = p - 4096;  // 2*32*32
        const int b = bid >> 10, qt = (bid >> 5) & 31, kt = bid & 31;
        const int r = tid >> 2, cs = tid & 3;
        const float* mp = mask + ((long)(b * S_LEN + qt * 64 + r)) * S_LEN + kt * 64 + cs * 16;
        int nz = 0;
#pragma unroll
        for (int j = 0; j < 4; ++j) {
            f32x4 a = *(const f32x4*)(mp + j * 4);
            nz |= (a[0] != 0.f) | (a[1] != 0.f) | (a[2] != 0.f) | (a[3] != 0.f);
        }
        unsigned long long ball = __ballot(nz);
        if ((tid & 63) == 0) wred[tid >> 6] = (ball != 0ull) ? 1 : 0;
        __syncthreads();
        if (tid == 0) flags[bid] = wred[0] | wred[1] | wred[2] | wred[3];
    }
}

// ---------------- GEMM epilogue (shared) ----------------
template <bool F32OUT, int TM>
static __device__ __forceinline__ void store_c(f32x4 (&acc)[TM][2],
                                               const float* __restrict__ bias,
                                               void* __restrict__ Cp, float oscale,
                                               bool vtout, int m0, int n0, int cidx, int kg) {
    if (vtout) {
        // V-transposed: row = token (b,s), col = channel (h,d); packed 8B stores.
        const int bb = m0 >> 11;  // batch (tile never crosses the 2048 boundary)
#pragma unroll
        for (int j = 0; j < 2; ++j) {
            int col = n0 + j * 16 + cidx;
            float bv = bias[col];
            u16* vt = (u16*)Cp + (((long)(bb * 8 + (col >> 6))) * 64 + (col & 63)) * S_LEN;
#pragma unroll
            for (int i = 0; i < TM; ++i) {
                int s = (m0 + i * 16 + kg * 4) & (S_LEN - 1);
                u32x2 d;
                d[0] = pk2bf(acc[i][j][0] + bv, acc[i][j][1] + bv);
                d[1] = pk2bf(acc[i][j][2] + bv, acc[i][j][3] + bv);
                *(u32x2*)(vt + s) = d;
            }
        }
        return;
    }
#pragma unroll
    for (int j = 0; j < 2; ++j) {
        int col = n0 + j * 16 + cidx;
        float bv = bias[col];
#pragma unroll
        for (int i = 0; i < TM; ++i) {
#pragma unroll
            for (int r = 0; r < 4; ++r) {
                int row = m0 + i * 16 + kg * 4 + r;
                float val = (acc[i][j][r] + bv) * oscale;
                if (F32OUT) {
                    ((float*)Cp)[(long)row * DMODEL + col] = val;
                } else {
                    ((u16*)Cp)[(long)row * DMODEL + col] = f2bf(val);
                }
            }
        }
    }
}

// ---------------- LDS-staged double-buffered GEMM ----------------
// C(4096x512) = A(4096x512,bf16) @ Wt^T + bias. Tile BM x 64, BK=32, 256 thr (4 waves 2x2),
// wave tile (BM/2) x 32. Padded LDS rows (40 u16 = 80B -> only 2-way bank aliasing, free).
// Pipeline: regs hold tile t+1; at iter t: write regs->LDS[buf^1], issue t+2 loads,
// compute tile t from LDS[buf], ONE barrier. Same proven structure as attn_kernel.
template <int BM, bool F32OUT>
static __device__ __forceinline__ void gemm_lds(const u16* __restrict__ Ag,
                                                const u16* __restrict__ Wg,
                                                const float* __restrict__ bias,
                                                void* __restrict__ Cp, float oscale,
                                                bool vtout, int bx, int by) {
    constexpr int MR = BM / 32;        // M fragments per wave
    constexpr int NCH = BM / 64 + 1;   // 16B staging chunks per thread per K-step
    __shared__ __align__(16) u16 As[2][BM][40];
    __shared__ __align__(16) u16 Bs[2][64][40];

    const int tid = threadIdx.x;
    const int lane = tid & 63;
    const int wave = tid >> 6;
    const int wr = wave >> 1, wc = wave & 1;
    const int cidx = lane & 15;
    const int kg = lane >> 4;

    // staging roles: chunk c = tid + 256*j ; c < BM*4 -> A[row=c>>2][seg=c&3] else B.
    const u16* gsrc[NCH];
    u16* ld0[NCH];
    u16* ld1[NCH];
#pragma unroll
    for (int j = 0; j < NCH; ++j) {
        int c = tid + 256 * j;
        if (c < BM * 4) {
            int r = c >> 2, s = c & 3;
            gsrc[j] = Ag + (long)(by * BM + r) * DMODEL + s * 8;
            ld0[j] = &As[0][r][s * 8];
            ld1[j] = &As[1][r][s * 8];
        } else {
            int c2 = c - BM * 4;
            int r = c2 >> 2, s = c2 & 3;
            gsrc[j] = Wg + (long)(bx * 64 + r) * DMODEL + s * 8;
            ld0[j] = &Bs[0][r][s * 8];
            ld1[j] = &Bs[1][r][s * 8];
        }
    }

    // prologue: tile0 -> LDS[0]; tile1 -> regs (in flight)
    u16x8 rg[NCH];
#pragma unroll
    for (int j = 0; j < NCH; ++j) rg[j] = *(const u16x8*)(gsrc[j]);
#pragma unroll
    for (int j = 0; j < NCH; ++j) *(u16x8*)(ld0[j]) = rg[j];
#pragma unroll
    for (int j = 0; j < NCH; ++j) rg[j] = *(const u16x8*)(gsrc[j] + 32);
    __syncthreads();

    const f32x4 fz = {0.f, 0.f, 0.f, 0.f};
    f32x4 acc[MR][2];
#pragma unroll
    for (int i = 0; i < MR; ++i)
#pragma unroll
        for (int j = 0; j < 2; ++j) acc[i][j] = fz;

    const int mw = wr * (BM / 2);
    const int nw = wc * 32;

#pragma unroll 2
    for (int t = 0; t < 16; ++t) {
        const int cur = t & 1;
        if (t + 1 < 16) {
#pragma unroll
            for (int j = 0; j < NCH; ++j) *(u16x8*)((cur ? ld0 : ld1)[j]) = rg[j];
            if (t + 2 < 16) {
#pragma unroll
                for (int j = 0; j < NCH; ++j) rg[j] = *(const u16x8*)(gsrc[j] + (t + 2) * 32);
            }
        }
        bf16x8 a[MR], b[2];
#pragma unroll
        for (int i = 0; i < MR; ++i) a[i] = ld8(&As[cur][mw + i * 16 + cidx][kg * 8]);
#pragma unroll
        for (int j = 0; j < 2; ++j) b[j] = ld8(&Bs[cur][nw + j * 16 + cidx][kg * 8]);
        __builtin_amdgcn_s_setprio(1);
#pragma unroll
        for (int i = 0; i < MR; ++i)
#pragma unroll
            for (int j = 0; j < 2; ++j)
                acc[i][j] = __builtin_amdgcn_mfma_f32_16x16x32_bf16(a[i], b[j], acc[i][j], 0, 0, 0);
        __builtin_amdgcn_s_setprio(0);
        __syncthreads();
    }

    store_c<F32OUT, MR>(acc, bias, Cp, oscale, vtout, by * BM + mw, bx * 64 + nw, cidx, kg);
}

// XCD-aware swizzle (T1): remap so the 8 bx-blocks sharing one A row-panel land on ONE XCD.
// Requires gridY % 8 == 0. Bijective.
static __device__ __forceinline__ void xcd_swizzle(int gridX, int gridY, int& bx, int& by) {
    const int flat = blockIdx.x + gridX * blockIdx.y;
    const int xcd = flat & 7;
    const int j = flat >> 3;
    by = xcd * (gridY >> 3) + j / gridX;
    bx = j % gridX;
}

// qkv: BM=128 -> grid (8,32,3) = 768 blocks = 3/CU, 30KB LDS.
__global__ __launch_bounds__(256) void qkv_gemm_kernel(
    const u16* __restrict__ Aqkv,
    const u16* __restrict__ wtall,
    const float* __restrict__ bq, const float* __restrict__ bk, const float* __restrict__ bv,
    u16* __restrict__ Q, u16* __restrict__ K, u16* __restrict__ Vt) {
    const u16* A = Aqkv + (long)blockIdx.z * 2097152;
    const u16* W = wtall + (long)(blockIdx.z + 1) * 262144;  // [wo, wq, wk, wv]
    const float* b;
    u16* C;
    float sc = 1.f;
    bool vt = false;
    if (blockIdx.z == 0) { b = bq; C = Q; sc = QSCALE; }  // fold 1/sqrt(DH)*log2e into Q
    else if (blockIdx.z == 1) { b = bk; C = K; }
    else { b = bv; C = Vt; vt = true; }
    int bx, by;
    xcd_swizzle(8, 32, bx, by);
    gemm_lds<128, false>(A, W, b, C, sc, vt, bx, by);
}

// out: BM=64 -> grid (8,64) = 512 blocks = 2/CU.
__global__ __launch_bounds__(256) void out_gemm_kernel(const u16* __restrict__ A,
                                                       const u16* __restrict__ Wt,
                                                       const float* __restrict__ bias,
                                                       float* __restrict__ C) {
    int bx, by;
    xcd_swizzle(8, 64, bx, by);
    gemm_lds<64, true>(A, Wt, bias, C, 1.f, false, bx, by);
}

// ---------------- flash attention, S^T formulation ----------------
// grid: (32, 16) remapped XCD-aware, block 256 (4 waves). Wave w owns 16 q-rows.
// QK^T computed transposed: D = K_tile . Q^T, so each lane holds 16 keys of ONE q-row.
// XCD swizzle; x2-unrolled main loop (compile-time dbuf index); row-sum L by ones-row
// MFMA; 2-tile-deep register prefetch; vote-based defer-max; in-kernel normalization.
__global__ __launch_bounds__(256) void attn_kernel(const u16* __restrict__ Q,
                                                   const u16* __restrict__ K,
                                                   const u16* __restrict__ Vt,
                                                   const float* __restrict__ mask,
                                                   const int* __restrict__ flags,
                                                   u16* __restrict__ Ab) {
    const int tid = threadIdx.x;
    const int lane = tid & 63;
    const int wave = tid >> 6;
    const int cidx = lane & 15;   // q-row (QK^T B-operand col / PV B-col); d-row for V A-frag
    const int kg = lane >> 4;
    // XCD-aware remap: XCD j gets F in [64j, 64j+64) = all 32 q-tiles of bh pair {2j, 2j+1}.
    const int flat = blockIdx.x + 32 * blockIdx.y;
    const int F = (flat & 7) * 64 + (flat >> 3);
    const int qt = F & 31;
    const int bh = F >> 5;
    const int b = bh >> 3, h = bh & 7;
    const int q0 = qt * 64 + wave * 16;

    __shared__ u16 kt_lds[2][64 * 64];   // [buf][key-local][dh], XOR-swizzled 8-blocks
    __shared__ u16 vt_lds[2][64 * 64];   // [buf][dh][key-local], XOR-swizzled
    __shared__ u16 p_lds[4][16 * 64];    // per-wave P^T as [q][key], XOR-swizzled
    u16* pw = p_lds[wave];

    // Q fragment: lane holds Q[q0+cidx][kg*8+j] (+32). Serves as B-operand of K.Q^T.
    const long qbase = ((long)(b * S_LEN + q0 + cidx)) * DMODEL + h * DHEAD + kg * 8;
    bf16x8 aq0 = ld8(Q + qbase);
    bf16x8 aq1 = ld8(Q + qbase + 32);

    // ones A-fragment: row 0 = 1.0, rows 1..15 = 0. mfma(ones, P^T) row 0 = sum_k P[q][k].
    bf16x8 onesf;
    {
        u16x8 t8;
        u16 ob = (cidx == 0) ? (u16)0x3F80 : (u16)0;
#pragma unroll
        for (int j = 0; j < 8; ++j) t8[j] = ob;
        onesf = *(bf16x8*)&t8;
    }

    const f32x4 fz = {0.f, 0.f, 0.f, 0.f};
    f32x4 acc[4];  // O^T accumulator: lane holds O[q0+cidx][16nt+4kg+r]
#pragma unroll
    for (int nt = 0; nt < 4; ++nt) acc[nt] = fz;
    f32x4 accL = fz;      // after ones-MFMA: lane q (kg==0), comp 0 holds running L[q]
    float mrow = -1e30f;  // per-lane: one q-row (log2 domain, deferred-max reference)

    // staging roles: 512 16B slots over 256 threads
    const int krow0 = tid >> 3, kseg0 = tid & 7;  // rows 0..31
    const int krow1 = krow0 + 32;                 // rows 32..63
    const u16* kgbase = K + ((long)(b * S_LEN)) * DMODEL + h * DHEAD;
    const u16* vgbase = Vt + ((long)bh * DHEAD) * S_LEN;
    const int kd0 = krow0 * 64 + (((kseg0 ^ (krow0 & 7))) << 3);
    const int kd1 = krow1 * 64 + (((kseg0 ^ (krow1 & 7))) << 3);
    const int* flagrow = flags + b * 1024 + qt * 32;
    const int NIT = S_LEN / 64;  // 32 (even -> clean x2 unroll)

    const u16* kp0 = kgbase + (long)krow0 * DMODEL + kseg0 * 8;
    const u16* kp1 = kgbase + (long)krow1 * DMODEL + kseg0 * 8;
    const u16* vp0 = vgbase + (long)krow0 * S_LEN + kseg0 * 8;
    const u16* vp1 = vgbase + (long)krow1 * S_LEN + kseg0 * 8;

    // prologue: tile 0 -> buf0, prefetch tile 1 into regs
    u16x8 rk0 = *(const u16x8*)kp0;
    u16x8 rk1 = *(const u16x8*)kp1;
    u16x8 rv0 = *(const u16x8*)vp0;
    u16x8 rv1 = *(const u16x8*)vp1;
    *(u16x8*)&kt_lds[0][kd0] = rk0;
    *(u16x8*)&kt_lds[0][kd1] = rk1;
    *(u16x8*)&vt_lds[0][kd0] = rv0;
    *(u16x8*)&vt_lds[0][kd1] = rv1;
    rk0 = *(const u16x8*)(kp0 + 64 * DMODEL);
    rk1 = *(const u16x8*)(kp1 + 64 * DMODEL);
    rv0 = *(const u16x8*)(vp0 + 64);
    rv1 = *(const u16x8*)(vp1 + 64);
    __syncthreads();

#define ATTN_TILE(IT, CUR)                                                                 \
    {                                                                                      \
        if ((IT) + 1 < NIT) {                                                              \
            u16* kn = kt_lds[(CUR) ^ 1];                                                   \
            u16* vn = vt_lds[(CUR) ^ 1];                                                   \
            *(u16x8*)&kn[kd0] = rk0;                                                       \
            *(u16x8*)&kn[kd1] = rk1;                                                       \
            *(u16x8*)&vn[kd0] = rv0;                                                       \
            *(u16x8*)&vn[kd1] = rv1;                                                       \
            if ((IT) + 2 < NIT) {                                                          \
                const int t2 = ((IT) + 2) * 64;                                            \
                rk0 = *(const u16x8*)(kp0 + (long)t2 * DMODEL);                            \
                rk1 = *(const u16x8*)(kp1 + (long)t2 * DMODEL);                            \
                rv0 = *(const u16x8*)(vp0 + t2);                                           \
                rv1 = *(const u16x8*)(vp1 + t2);                                           \
            }                                                                              \
        }                                                                                  \
        const int flg = flagrow[(IT)];                                                     \
        const u16* kb = kt_lds[(CUR)];                                                     \
        const u16* vb = vt_lds[(CUR)];                                                     \
        f32x4 sacc[4];                                                                     \
        _Pragma("unroll")                                                                  \
        for (int ct = 0; ct < 4; ++ct) sacc[ct] = fz;                                      \
        __builtin_amdgcn_s_setprio(1);                                                     \
        _Pragma("unroll")                                                                  \
        for (int ct = 0; ct < 4; ++ct) {                                                   \
            int r = ct * 16 + cidx;                                                        \
            bf16x8 kv0 = ld8(&kb[r * 64 + ((kg ^ (r & 7)) << 3)]);                         \
            bf16x8 kv1 = ld8(&kb[r * 64 + (((4 ^ kg) ^ (r & 7)) << 3)]);                   \
            sacc[ct] = __builtin_amdgcn_mfma_f32_16x16x32_bf16(kv0, aq0, sacc[ct], 0, 0, 0); \
            sacc[ct] = __builtin_amdgcn_mfma_f32_16x16x32_bf16(kv1, aq1, sacc[ct], 0, 0, 0); \
        }                                                                                  \
        __builtin_amdgcn_s_setprio(0);                                                     \
        if (flg) {                                                                         \
            const float* mb = mask + ((long)(b * S_LEN + q0 + cidx)) * S_LEN + (IT) * 64 + kg * 4; \
            _Pragma("unroll")                                                              \
            for (int ct = 0; ct < 4; ++ct) {                                               \
                f32x4 mv = *(const f32x4*)(mb + ct * 16);                                  \
                _Pragma("unroll")                                                          \
                for (int r = 0; r < 4; ++r) sacc[ct][r] -= MASKC * mv[r];                  \
            }                                                                              \
        }                                                                                  \
        float t0 = fmax3(sacc[0][0], sacc[0][1], sacc[0][2]);                              \
        float t1 = fmax3(sacc[0][3], sacc[1][0], sacc[1][1]);                              \
        float t2 = fmax3(sacc[1][2], sacc[1][3], sacc[2][0]);                              \
        float t3 = fmax3(sacc[2][1], sacc[2][2], sacc[2][3]);                              \
        float t4 = fmax3(sacc[3][0], sacc[3][1], sacc[3][2]);                              \
        float mxl = __builtin_fmaxf(fmax3(fmax3(t0, t1, t2), t3, t4), sacc[3][3]);         \
        if (__any(mxl > mrow + RESCALE_THR)) {                                             \
            float mx = fmaxf(mxl, __shfl_xor(mxl, 16));                                    \
            mx = fmaxf(mx, __shfl_xor(mx, 32));                                            \
            float mnew = fmaxf(mrow, mx);                                                  \
            float alpha = __builtin_amdgcn_exp2f(mrow - mnew);                             \
            mrow = mnew;                                                                   \
            accL = accL * alpha;                                                           \
            _Pragma("unroll")                                                              \
            for (int nt = 0; nt < 4; ++nt) acc[nt] = acc[nt] * alpha;                      \
        }                                                                                  \
        _Pragma("unroll")                                                                  \
        for (int ct = 0; ct < 4; ++ct)                                                     \
            _Pragma("unroll")                                                              \
            for (int r = 0; r < 4; ++r)                                                    \
                sacc[ct][r] = __builtin_amdgcn_exp2f(sacc[ct][r] - mrow);                  \
        _Pragma("unroll")                                                                  \
        for (int ct = 0; ct < 4; ++ct) {                                                   \
            u32x2 d;                                                                       \
            d[0] = pk2bf(sacc[ct][0], sacc[ct][1]);                                        \
            d[1] = pk2bf(sacc[ct][2], sacc[ct][3]);                                        \
            int blk = 2 * ct + (kg >> 1);                                                  \
            *(u32x2*)&pw[cidx * 64 + ((blk ^ (cidx & 7)) << 3) + (kg & 1) * 4] = d;        \
        }                                                                                  \
        bf16x8 pf0 = ld8(&pw[cidx * 64 + ((kg ^ (cidx & 7)) << 3)]);                       \
        bf16x8 pf1 = ld8(&pw[cidx * 64 + (((4 ^ kg) ^ (cidx & 7)) << 3)]);                 \
        __builtin_amdgcn_s_setprio(1);                                                     \
        _Pragma("unroll")                                                                  \
        for (int nt = 0; nt < 4; ++nt) {                                                   \
            int rr = nt * 16 + cidx;                                                       \
            bf16x8 v0 = ld8(&vb[rr * 64 + ((kg ^ (rr & 7)) << 3)]);                        \
            bf16x8 v1 = ld8(&vb[rr * 64 + (((4 ^ kg) ^ (rr & 7)) << 3)]);                  \
            acc[nt] = __builtin_amdgcn_mfma_f32_16x16x32_bf16(v0, pf0, acc[nt], 0, 0, 0);  \
            acc[nt] = __builtin_amdgcn_mfma_f32_16x16x32_bf16(v1, pf1, acc[nt], 0, 0, 0);  \
        }                                                                                  \
        accL = __builtin_amdgcn_mfma_f32_16x16x32_bf16(onesf, pf0, accL, 0, 0, 0);         \
        accL = __builtin_amdgcn_mfma_f32_16x16x32_bf16(onesf, pf1, accL, 0, 0, 0);         \
        __builtin_amdgcn_s_setprio(0);                                                     \
        __syncthreads();                                                                   \
    }

    for (int it = 0; it < NIT; it += 2) {
        ATTN_TILE(it, 0)
        ATTN_TILE(it + 1, 1)
    }
#undef ATTN_TILE

    // epilogue: L[q] sits in lane q (kg==0), comp 0 — broadcast, normalize, write bf16 Ab.
    float Lb = __shfl(accL[0], cidx);
    float invL = 1.f / Lb;
    const long abase = ((long)(b * S_LEN + q0 + cidx)) * DMODEL + h * DHEAD;
#pragma unroll
    for (int nt = 0; nt < 4; ++nt) {
        u32x2 d;
        d[0] = pk2bf(acc[nt][0] * invL, acc[nt][1] * invL);
        d[1] = pk2bf(acc[nt][2] * invL, acc[nt][3] * invL);
        *(u32x2*)(Ab + abase + nt * 16 + kg * 4) = d;
    }
}

extern "C" void kernel_launch(void* const* d_in, const int* in_sizes, int n_in,
                              void* d_out, int out_size, void* d_ws, size_t ws_size,
                              hipStream_t stream) {
    const float* q_in = (const float*)d_in[0];
    const float* k_in = (const float*)d_in[1];
    const float* v_in = (const float*)d_in[2];
    const float* mask = (const float*)d_in[3];
    const float* wq = (const float*)d_in[4];
    const float* bq = (const float*)d_in[5];
    const float* wk = (const float*)d_in[6];
    const float* bk = (const float*)d_in[7];
    const float* wv = (const float*)d_in[8];
    const float* bv = (const float*)d_in[9];
    const float* wo = (const float*)d_in[10];
    const float* bo = (const float*)d_in[11];

    // ws layout (u16 units):
    u16* ws = (u16*)d_ws;
    u16* Qb = ws;                       // 2.1M  projected Q (pre-scaled QSCALE)
    u16* Kb = Qb + 2097152;             // 2.1M
    u16* Vt = Kb + 2097152;             // 2.1M  V transposed (B,H,DH,S) - written by qkv_gemm
    u16* wtall = Vt + 2097152;          // 4 x 262144: [wo, wq, wk, wv]
    u16* Sreg = wtall + 4 * 262144;     // 3 x 2.1M: Aq,Ak,Av  (dead after qkv_gemm)
    u16* Ab = Sreg + 3 * 2097152;       // 2.1M  attention output (merged heads)
    int* mflags = (int*)(Ab + 2097152); // 2048 ints

    prep_kernel<<<6144, 256, 0, stream>>>(q_in, k_in, v_in, wq, wk, wv, wo, mask,
                                          Sreg, wtall, mflags);
    qkv_gemm_kernel<<<dim3(8, 32, 3), 256, 0, stream>>>(Sreg, wtall, bq, bk, bv, Qb, Kb, Vt);
    attn_kernel<<<dim3(32, 16), 256, 0, stream>>>(Qb, Kb, Vt, mask, mflags, Ab);
    out_gemm_kernel<<<dim3(8, 64), 256, 0, stream>>>(Ab, wtall, bo, (float*)d_out);
}